// Round 1
// baseline (630.170 us; speedup 1.0000x reference)
//
#include <hip/hip_runtime.h>
#include <hip/hip_bf16.h>

// GLA block: LN -> QKV -> ELU linear attention + depthwise conv -> gated mix -> out proj + residual
// B=4 T=4096 D=1024 H=16 HD=64 K=3
#define B_ 4
#define T_ 4096
#define D_ 1024
#define H_ 16
#define M_ (B_*T_)      // 16384 rows

typedef short bf16x8 __attribute__((ext_vector_type(8)));
typedef float f32x4 __attribute__((ext_vector_type(4)));

__device__ __forceinline__ float b2f(unsigned short h){
  union { unsigned u; float f; } x; x.u = ((unsigned)h) << 16; return x.f;
}
__device__ __forceinline__ unsigned short f2b(float f){
  union { float f; unsigned u; } x; x.f = f;
  unsigned r = x.u + 0x7FFFu + ((x.u >> 16) & 1u);   // RNE
  return (unsigned short)(r >> 16);
}

// async global->LDS, 16B per lane. LDS dst must be wave-uniform (HW scatters lane*16).
__device__ __forceinline__ void ld_lds16(const unsigned short* g, unsigned short* l){
  __builtin_amdgcn_global_load_lds(
      (const __attribute__((address_space(1))) unsigned int*)(unsigned long long)g,
      (__attribute__((address_space(3))) unsigned int*)(unsigned int)(unsigned long long)l,
      16, 0, 0);
}

// ---------------- fp32 -> bf16 weight convert ----------------
__global__ __launch_bounds__(256) void f32_to_bf16(const float* __restrict__ src,
                                                   unsigned short* __restrict__ dst, int n){
  int i = (blockIdx.x*256 + threadIdx.x)*4;
  if (i < n){
    float4 v = *(const float4*)(src + i);
    ushort4 o; o.x=f2b(v.x); o.y=f2b(v.y); o.z=f2b(v.z); o.w=f2b(v.w);
    *(ushort4*)(dst + i) = o;
  }
}

// ---------------- dual LayerNorm (shared mean/var) ----------------
__global__ __launch_bounds__(256) void ln_dual(
    const float* __restrict__ x,
    const float* __restrict__ g1, const float* __restrict__ b1,
    const float* __restrict__ g2, const float* __restrict__ b2,
    unsigned short* __restrict__ xn, unsigned short* __restrict__ xg){
  int row = blockIdx.x;
  int tid = threadIdx.x;
  const float4* xr = (const float4*)(x + (size_t)row*D_);
  float4 v = xr[tid];
  float s  = v.x+v.y+v.z+v.w;
  float ss = v.x*v.x + v.y*v.y + v.z*v.z + v.w*v.w;
  #pragma unroll
  for (int o=32;o>0;o>>=1){ s += __shfl_down(s,o,64); ss += __shfl_down(ss,o,64); }
  __shared__ float red[8];
  int lane = tid & 63, wv = tid >> 6;
  if (lane==0){ red[wv]=s; red[4+wv]=ss; }
  __syncthreads();
  s  = red[0]+red[1]+red[2]+red[3];
  ss = red[4]+red[5]+red[6]+red[7];
  float mean = s * (1.f/D_);
  float var  = ss*(1.f/D_) - mean*mean;
  float inv  = rsqrtf(var + 1e-5f);
  int c = tid*4;
  float4 ga = *(const float4*)(g1+c), ba = *(const float4*)(b1+c);
  float4 gb = *(const float4*)(g2+c), bb = *(const float4*)(b2+c);
  float nx=(v.x-mean)*inv, ny=(v.y-mean)*inv, nz=(v.z-mean)*inv, nw=(v.w-mean)*inv;
  size_t base = (size_t)row*D_ + c;
  ushort4 o1, o2;
  o1.x=f2b(nx*ga.x+ba.x); o1.y=f2b(ny*ga.y+ba.y); o1.z=f2b(nz*ga.z+ba.z); o1.w=f2b(nw*ga.w+ba.w);
  o2.x=f2b(nx*gb.x+bb.x); o2.y=f2b(ny*gb.y+bb.y); o2.z=f2b(nz*gb.z+bb.z); o2.w=f2b(nw*gb.w+bb.w);
  *(ushort4*)(xn+base) = o1;
  *(ushort4*)(xg+base) = o2;
}

// ---------------- bf16 MFMA GEMM: C[m,n] = sum_k A[m,k]*Bw[n,k] (+epilogue) ----------------
// EPI 0: store bf16 raw. EPI 1: +bias, sigmoid, store bf16. EPI 2: +bias+resid, store fp32.
template<int EPI>
__global__ __launch_bounds__(256, 3) void gemm_bt(
    const unsigned short* __restrict__ A, const unsigned short* __restrict__ Bw,
    int N, int K,
    const float* __restrict__ bias, const float* __restrict__ resid,
    unsigned short* __restrict__ Cb, float* __restrict__ Cf){
  __shared__ unsigned short sA[128*32];
  __shared__ unsigned short sB[128*32];
  int tid = threadIdx.x;
  int lane = tid & 63, wv = tid >> 6;
  int m0 = blockIdx.x * 128, n0 = blockIdx.y * 128;
  // staging addresses: wave wv covers rows [wv*32, wv*32+32) via two 1KB chunks
  int srow = wv*32 + (lane>>2);
  int scol = (lane&3)*8;
  const unsigned short* gA = A + (size_t)(m0+srow)*K + scol;
  const unsigned short* gB = Bw + (size_t)(n0+srow)*K + scol;
  unsigned short* lA = sA + wv*1024;   // wave-uniform
  unsigned short* lB = sB + wv*1024;
  f32x4 zero = {0.f,0.f,0.f,0.f};
  f32x4 acc[4][4];
  #pragma unroll
  for (int i=0;i<4;i++){ acc[i][0]=zero; acc[i][1]=zero; acc[i][2]=zero; acc[i][3]=zero; }
  int wm = wv & 1, wn = wv >> 1;
  int fr = lane & 15;          // fragment row (m for A, n for B)
  int fk = (lane >> 4) * 8;    // fragment k offset
  for (int kk = 0; kk < K; kk += 32){
    __syncthreads();
    ld_lds16(gA,              lA);
    ld_lds16(gA + (size_t)16*K, lA + 512);
    ld_lds16(gB,              lB);
    ld_lds16(gB + (size_t)16*K, lB + 512);
    gA += 32; gB += 32;
    __syncthreads();   // drains vmcnt before barrier -> LDS valid
    bf16x8 af[4], bfr[4];
    #pragma unroll
    for (int i=0;i<4;i++) af[i]  = *(const bf16x8*)(sA + (wm*64 + i*16 + fr)*32 + fk);
    #pragma unroll
    for (int j=0;j<4;j++) bfr[j] = *(const bf16x8*)(sB + (wn*64 + j*16 + fr)*32 + fk);
    #pragma unroll
    for (int i=0;i<4;i++)
      #pragma unroll
      for (int j=0;j<4;j++)
        acc[i][j] = __builtin_amdgcn_mfma_f32_16x16x32_bf16(af[i], bfr[j], acc[i][j], 0,0,0);
  }
  // epilogue: C/D layout col=lane&15, row=(lane>>4)*4+reg
  int er = (lane>>4)*4;
  int ec = lane & 15;
  #pragma unroll
  for (int i=0;i<4;i++){
    #pragma unroll
    for (int r=0;r<4;r++){
      int m = m0 + wm*64 + i*16 + er + r;
      size_t rowoff = (size_t)m * N;
      #pragma unroll
      for (int j=0;j<4;j++){
        int n = n0 + wn*64 + j*16 + ec;
        float v = acc[i][j][r];
        if (EPI == 0){
          Cb[rowoff + n] = f2b(v);
        } else if (EPI == 1){
          v += bias[n];
          v = 1.f/(1.f + __expf(-v));
          Cb[rowoff + n] = f2b(v);
        } else {
          v += bias[n] + resid[rowoff + n];
          Cf[rowoff + n] = v;
        }
      }
    }
  }
}

// ---------------- kv partials: kv[b,h,d,e] = sum_t phi_k[t,d]*v[t,e] ----------------
__global__ __launch_bounds__(256) void kv_partial(const unsigned short* __restrict__ qkv,
                                                  float* __restrict__ part){
  int bh = blockIdx.x, chunk = blockIdx.y;
  int b = bh >> 4, h = bh & 15;
  int tid = threadIdx.x;
  int d = tid & 63, wv = tid >> 6;
  __shared__ float sk[512], sv[512];    // 8 timesteps x 64
  float acc[16];
  #pragma unroll
  for (int j=0;j<16;j++) acc[j] = 0.f;
  size_t base = ((size_t)(b*T_) + (size_t)chunk*512) * 3072 + h*64;
  for (int ts=0; ts<512; ts+=8){
    __syncthreads();
    int li = tid & 127;
    int tt = li >> 4;
    int e  = (li & 15) * 4;
    size_t off = base + (size_t)(ts+tt)*3072 + e;
    if (tid < 128){
      ushort4 kr = *(const ushort4*)(qkv + off + 1024);
      float k0=b2f(kr.x), k1=b2f(kr.y), k2=b2f(kr.z), k3=b2f(kr.w);
      float4 ph;
      ph.x = k0>0.f ? k0+1.f : __expf(k0);
      ph.y = k1>0.f ? k1+1.f : __expf(k1);
      ph.z = k2>0.f ? k2+1.f : __expf(k2);
      ph.w = k3>0.f ? k3+1.f : __expf(k3);
      *(float4*)(sk + tt*64 + e) = ph;
    } else {
      ushort4 vr = *(const ushort4*)(qkv + off + 2048);
      float4 vv; vv.x=b2f(vr.x); vv.y=b2f(vr.y); vv.z=b2f(vr.z); vv.w=b2f(vr.w);
      *(float4*)(sv + tt*64 + e) = vv;
    }
    __syncthreads();
    #pragma unroll
    for (int t8=0;t8<8;t8++){
      float pk = sk[t8*64 + d];
      const float4* v4 = (const float4*)(sv + t8*64 + wv*16);
      float4 a0=v4[0], a1=v4[1], a2=v4[2], a3=v4[3];
      acc[0] +=pk*a0.x; acc[1] +=pk*a0.y; acc[2] +=pk*a0.z; acc[3] +=pk*a0.w;
      acc[4] +=pk*a1.x; acc[5] +=pk*a1.y; acc[6] +=pk*a1.z; acc[7] +=pk*a1.w;
      acc[8] +=pk*a2.x; acc[9] +=pk*a2.y; acc[10]+=pk*a2.z; acc[11]+=pk*a2.w;
      acc[12]+=pk*a3.x; acc[13]+=pk*a3.y; acc[14]+=pk*a3.z; acc[15]+=pk*a3.w;
    }
  }
  float* pp = part + (((size_t)chunk*64 + bh)*4096) + d*64 + wv*16;
  #pragma unroll
  for (int j=0;j<16;j++) pp[j] = acc[j];
}

__global__ __launch_bounds__(256) void kv_reduce(const float* __restrict__ part,
                                                 float* __restrict__ kv){
  int i = blockIdx.x*256 + threadIdx.x;    // 64*4096 total
  float s = 0.f;
  #pragma unroll
  for (int c=0;c<8;c++) s += part[(size_t)c*262144 + i];
  kv[i] = s;
}

// ---------------- fused y_att matvec + depthwise conv + gated combine ----------------
// y[b,t,d] = g*(phi_q . kv[:,d]) + (1-g)*conv(xn); one block = 8 rows, thread d owns kv column in regs
__global__ __launch_bounds__(1024) void attn_combine(
    const unsigned short* __restrict__ qkv, const float* __restrict__ kv,
    const unsigned short* __restrict__ xn, const unsigned short* __restrict__ gsig,
    const float* __restrict__ conv_w, const float* __restrict__ conv_b,
    unsigned short* __restrict__ y){
  int bt0 = blockIdx.x * 8;
  int b = bt0 >> 12;
  int d = threadIdx.x;
  int h = d >> 6, e = d & 63;
  __shared__ float sq[8*1024];
  #pragma unroll
  for (int tt=0;tt<8;tt++){
    float qv = b2f(qkv[(size_t)(bt0+tt)*3072 + d]);
    sq[tt*1024 + d] = qv>0.f ? qv+1.f : __expf(qv);
  }
  __syncthreads();
  float col[64];
  const float* kvp = kv + ((size_t)(b*16 + h))*4096 + e;
  #pragma unroll
  for (int dd=0;dd<64;dd++) col[dd] = kvp[dd*64];
  float w0 = conv_w[d*3], w1 = conv_w[d*3+1], w2 = conv_w[d*3+2], cb = conv_b[d];
  int tl0 = bt0 & (T_-1);
  for (int tt=0;tt<8;tt++){
    const float4* q4 = (const float4*)(sq + tt*1024 + h*64);
    float ya = 0.f;
    #pragma unroll
    for (int q=0;q<16;q++){
      float4 qq = q4[q];
      ya += qq.x*col[q*4] + qq.y*col[q*4+1] + qq.z*col[q*4+2] + qq.w*col[q*4+3];
    }
    int t = tl0 + tt;
    size_t base = (size_t)(bt0+tt)*1024 + d;
    float xm = (t>0)      ? b2f(xn[base-1024]) : 0.f;
    float xc =              b2f(xn[base]);
    float xp = (t<T_-1)   ? b2f(xn[base+1024]) : 0.f;
    float yl = xm*w0 + xc*w1 + xp*w2 + cb;
    float gg = b2f(gsig[base]);
    y[base] = f2b(gg*ya + (1.f-gg)*yl);
  }
}

extern "C" void kernel_launch(void* const* d_in, const int* in_sizes, int n_in,
                              void* d_out, int out_size, void* d_ws, size_t ws_size,
                              hipStream_t stream){
  const float* x      = (const float*)d_in[0];
  const float* ln_g   = (const float*)d_in[1];
  const float* ln_b   = (const float*)d_in[2];
  const float* w_qkv  = (const float*)d_in[3];
  const float* conv_w = (const float*)d_in[4];
  const float* conv_b = (const float*)d_in[5];
  const float* gln_g  = (const float*)d_in[6];
  const float* gln_b  = (const float*)d_in[7];
  const float* w_gate = (const float*)d_in[8];
  const float* b_gate = (const float*)d_in[9];
  const float* w_out  = (const float*)d_in[10];
  const float* b_out  = (const float*)d_in[11];
  float* out = (float*)d_out;

  char* ws = (char*)d_ws;
  size_t off = 0;
  auto alloc = [&](size_t bytes){ void* p = ws + off; off += (bytes + 255) & ~(size_t)255; return p; };
  unsigned short* wqkv_b  = (unsigned short*)alloc((size_t)3072*1024*2);
  unsigned short* wgate_b = (unsigned short*)alloc((size_t)1024*1024*2);
  unsigned short* wout_b  = (unsigned short*)alloc((size_t)1024*1024*2);
  unsigned short* xn      = (unsigned short*)alloc((size_t)M_*D_*2);
  unsigned short* xg      = (unsigned short*)alloc((size_t)M_*D_*2);
  unsigned short* qkv     = (unsigned short*)alloc((size_t)M_*3072*2);
  unsigned short* gy      = (unsigned short*)alloc((size_t)M_*D_*2);  // gate sigmoid, later reused as y
  float* part             = (float*)alloc((size_t)8*64*4096*4);
  float* kvbuf            = (float*)alloc((size_t)64*4096*4);
  // total ~222 MB of d_ws

  f32_to_bf16<<<3072*1024/1024, 256, 0, stream>>>(w_qkv,  wqkv_b,  3072*1024);
  f32_to_bf16<<<1024*1024/1024, 256, 0, stream>>>(w_gate, wgate_b, 1024*1024);
  f32_to_bf16<<<1024*1024/1024, 256, 0, stream>>>(w_out,  wout_b,  1024*1024);

  ln_dual<<<M_, 256, 0, stream>>>(x, ln_g, ln_b, gln_g, gln_b, xn, xg);

  // qkv = xn @ w_qkv^T   [16384,3072]
  gemm_bt<0><<<dim3(128,24), 256, 0, stream>>>(xn, wqkv_b, 3072, 1024, nullptr, nullptr, qkv, nullptr);

  // kv state per (b,h)
  kv_partial<<<dim3(64,8), 256, 0, stream>>>(qkv, part);
  kv_reduce<<<1024, 256, 0, stream>>>(part, kvbuf);

  // g = sigmoid(xg @ w_gate^T + b_gate)
  gemm_bt<1><<<dim3(128,8), 256, 0, stream>>>(xg, wgate_b, 1024, 1024, b_gate, nullptr, gy, nullptr);

  // y = g*y_att + (1-g)*y_local   (writes over gy in place, same-index only)
  attn_combine<<<2048, 1024, 0, stream>>>(qkv, kvbuf, xn, gy, conv_w, conv_b, gy);

  // out = x + y @ w_out^T + b_out
  gemm_bt<2><<<dim3(128,8), 256, 0, stream>>>(gy, wout_b, 1024, 1024, b_out, x, nullptr, out);
}

// Round 2
// 498.865 us; speedup vs baseline: 1.2632x; 1.2632x over previous
//
#include <hip/hip_runtime.h>
#include <hip/hip_bf16.h>

// GLA block: LN -> QKV -> ELU linear attention + depthwise conv -> gated mix -> out proj + residual
// B=4 T=4096 D=1024 H=16 HD=64 K=3
#define B_ 4
#define T_ 4096
#define D_ 1024
#define H_ 16
#define M_ (B_*T_)      // 16384 rows

typedef short bf16x8 __attribute__((ext_vector_type(8)));
typedef float f32x4 __attribute__((ext_vector_type(4)));

__device__ __forceinline__ float b2f(unsigned short h){
  union { unsigned u; float f; } x; x.u = ((unsigned)h) << 16; return x.f;
}
__device__ __forceinline__ unsigned short f2b(float f){
  union { float f; unsigned u; } x; x.f = f;
  unsigned r = x.u + 0x7FFFu + ((x.u >> 16) & 1u);   // RNE
  return (unsigned short)(r >> 16);
}

// async global->LDS, 16B per lane. LDS dst must be wave-uniform (HW scatters lane*16).
__device__ __forceinline__ void ld_lds16(const unsigned short* g, unsigned short* l){
  __builtin_amdgcn_global_load_lds(
      (const __attribute__((address_space(1))) unsigned int*)(unsigned long long)g,
      (__attribute__((address_space(3))) unsigned int*)(unsigned int)(unsigned long long)l,
      16, 0, 0);
}

// ---------------- fp32 -> bf16 weight convert ----------------
__global__ __launch_bounds__(256) void f32_to_bf16(const float* __restrict__ src,
                                                   unsigned short* __restrict__ dst, int n){
  int i = (blockIdx.x*256 + threadIdx.x)*4;
  if (i < n){
    float4 v = *(const float4*)(src + i);
    ushort4 o; o.x=f2b(v.x); o.y=f2b(v.y); o.z=f2b(v.z); o.w=f2b(v.w);
    *(ushort4*)(dst + i) = o;
  }
}

// ---------------- dual LayerNorm (shared mean/var) ----------------
__global__ __launch_bounds__(256) void ln_dual(
    const float* __restrict__ x,
    const float* __restrict__ g1, const float* __restrict__ b1,
    const float* __restrict__ g2, const float* __restrict__ b2,
    unsigned short* __restrict__ xn, unsigned short* __restrict__ xg){
  int row = blockIdx.x;
  int tid = threadIdx.x;
  const float4* xr = (const float4*)(x + (size_t)row*D_);
  float4 v = xr[tid];
  float s  = v.x+v.y+v.z+v.w;
  float ss = v.x*v.x + v.y*v.y + v.z*v.z + v.w*v.w;
  #pragma unroll
  for (int o=32;o>0;o>>=1){ s += __shfl_down(s,o,64); ss += __shfl_down(ss,o,64); }
  __shared__ float red[8];
  int lane = tid & 63, wv = tid >> 6;
  if (lane==0){ red[wv]=s; red[4+wv]=ss; }
  __syncthreads();
  s  = red[0]+red[1]+red[2]+red[3];
  ss = red[4]+red[5]+red[6]+red[7];
  float mean = s * (1.f/D_);
  float var  = ss*(1.f/D_) - mean*mean;
  float inv  = rsqrtf(var + 1e-5f);
  int c = tid*4;
  float4 ga = *(const float4*)(g1+c), ba = *(const float4*)(b1+c);
  float4 gb = *(const float4*)(g2+c), bb = *(const float4*)(b2+c);
  float nx=(v.x-mean)*inv, ny=(v.y-mean)*inv, nz=(v.z-mean)*inv, nw=(v.w-mean)*inv;
  size_t base = (size_t)row*D_ + c;
  ushort4 o1, o2;
  o1.x=f2b(nx*ga.x+ba.x); o1.y=f2b(ny*ga.y+ba.y); o1.z=f2b(nz*ga.z+ba.z); o1.w=f2b(nw*ga.w+ba.w);
  o2.x=f2b(nx*gb.x+bb.x); o2.y=f2b(ny*gb.y+bb.y); o2.z=f2b(nz*gb.z+bb.z); o2.w=f2b(nw*gb.w+bb.w);
  *(ushort4*)(xn+base) = o1;
  *(ushort4*)(xg+base) = o2;
}

// ---------------- bf16 MFMA GEMM: C[m,n] = sum_k A[m,k]*Bw[n,k] (+epilogue) ----------------
// EPI 0: store bf16 raw. EPI 1: +bias, sigmoid, store bf16. EPI 2: +bias+resid, store fp32.
template<int EPI>
__global__ __launch_bounds__(256, 3) void gemm_bt(
    const unsigned short* __restrict__ A, const unsigned short* __restrict__ Bw,
    int N, int K,
    const float* __restrict__ bias, const float* __restrict__ resid,
    unsigned short* __restrict__ Cb, float* __restrict__ Cf){
  __shared__ unsigned short sA[128*32];
  __shared__ unsigned short sB[128*32];
  int tid = threadIdx.x;
  int lane = tid & 63, wv = tid >> 6;
  int m0 = blockIdx.x * 128, n0 = blockIdx.y * 128;
  int srow = wv*32 + (lane>>2);
  int scol = (lane&3)*8;
  const unsigned short* gA = A + (size_t)(m0+srow)*K + scol;
  const unsigned short* gB = Bw + (size_t)(n0+srow)*K + scol;
  unsigned short* lA = sA + wv*1024;   // wave-uniform
  unsigned short* lB = sB + wv*1024;
  f32x4 zero = {0.f,0.f,0.f,0.f};
  f32x4 acc[4][4];
  #pragma unroll
  for (int i=0;i<4;i++){ acc[i][0]=zero; acc[i][1]=zero; acc[i][2]=zero; acc[i][3]=zero; }
  int wm = wv & 1, wn = wv >> 1;
  int fr = lane & 15;
  int fk = (lane >> 4) * 8;
  for (int kk = 0; kk < K; kk += 32){
    __syncthreads();
    ld_lds16(gA,              lA);
    ld_lds16(gA + (size_t)16*K, lA + 512);
    ld_lds16(gB,              lB);
    ld_lds16(gB + (size_t)16*K, lB + 512);
    gA += 32; gB += 32;
    __syncthreads();
    bf16x8 af[4], bfr[4];
    #pragma unroll
    for (int i=0;i<4;i++) af[i]  = *(const bf16x8*)(sA + (wm*64 + i*16 + fr)*32 + fk);
    #pragma unroll
    for (int j=0;j<4;j++) bfr[j] = *(const bf16x8*)(sB + (wn*64 + j*16 + fr)*32 + fk);
    #pragma unroll
    for (int i=0;i<4;i++)
      #pragma unroll
      for (int j=0;j<4;j++)
        acc[i][j] = __builtin_amdgcn_mfma_f32_16x16x32_bf16(af[i], bfr[j], acc[i][j], 0,0,0);
  }
  int er = (lane>>4)*4;
  int ec = lane & 15;
  #pragma unroll
  for (int i=0;i<4;i++){
    #pragma unroll
    for (int r=0;r<4;r++){
      int m = m0 + wm*64 + i*16 + er + r;
      size_t rowoff = (size_t)m * N;
      #pragma unroll
      for (int j=0;j<4;j++){
        int n = n0 + wn*64 + j*16 + ec;
        float v = acc[i][j][r];
        if (EPI == 0){
          Cb[rowoff + n] = f2b(v);
        } else if (EPI == 1){
          v += bias[n];
          v = 1.f/(1.f + __expf(-v));
          Cb[rowoff + n] = f2b(v);
        } else {
          v += bias[n] + resid[rowoff + n];
          Cf[rowoff + n] = v;
        }
      }
    }
  }
}

// ---------------- kv partials: kv[b,h,d,e] = sum_t phi_k[t,d]*v[t,e] ----------------
__global__ __launch_bounds__(256) void kv_partial(const unsigned short* __restrict__ qkv,
                                                  float* __restrict__ part){
  int bh = blockIdx.x, chunk = blockIdx.y;
  int b = bh >> 4, h = bh & 15;
  int tid = threadIdx.x;
  int d = tid & 63, wv = tid >> 6;
  __shared__ float sk[512], sv[512];    // 8 timesteps x 64
  float acc[16];
  #pragma unroll
  for (int j=0;j<16;j++) acc[j] = 0.f;
  size_t base = ((size_t)(b*T_) + (size_t)chunk*512) * 3072 + h*64;
  for (int ts=0; ts<512; ts+=8){
    __syncthreads();
    int li = tid & 127;
    int tt = li >> 4;
    int e  = (li & 15) * 4;
    size_t off = base + (size_t)(ts+tt)*3072 + e;
    if (tid < 128){
      ushort4 kr = *(const ushort4*)(qkv + off + 1024);
      float k0=b2f(kr.x), k1=b2f(kr.y), k2=b2f(kr.z), k3=b2f(kr.w);
      float4 ph;
      ph.x = k0>0.f ? k0+1.f : __expf(k0);
      ph.y = k1>0.f ? k1+1.f : __expf(k1);
      ph.z = k2>0.f ? k2+1.f : __expf(k2);
      ph.w = k3>0.f ? k3+1.f : __expf(k3);
      *(float4*)(sk + tt*64 + e) = ph;
    } else {
      ushort4 vr = *(const ushort4*)(qkv + off + 2048);
      float4 vv; vv.x=b2f(vr.x); vv.y=b2f(vr.y); vv.z=b2f(vr.z); vv.w=b2f(vr.w);
      *(float4*)(sv + tt*64 + e) = vv;
    }
    __syncthreads();
    #pragma unroll
    for (int t8=0;t8<8;t8++){
      float pk = sk[t8*64 + d];
      const float4* v4 = (const float4*)(sv + t8*64 + wv*16);
      float4 a0=v4[0], a1=v4[1], a2=v4[2], a3=v4[3];
      acc[0] +=pk*a0.x; acc[1] +=pk*a0.y; acc[2] +=pk*a0.z; acc[3] +=pk*a0.w;
      acc[4] +=pk*a1.x; acc[5] +=pk*a1.y; acc[6] +=pk*a1.z; acc[7] +=pk*a1.w;
      acc[8] +=pk*a2.x; acc[9] +=pk*a2.y; acc[10]+=pk*a2.z; acc[11]+=pk*a2.w;
      acc[12]+=pk*a3.x; acc[13]+=pk*a3.y; acc[14]+=pk*a3.z; acc[15]+=pk*a3.w;
    }
  }
  float* pp = part + (((size_t)chunk*64 + bh)*4096) + d*64 + wv*16;
  #pragma unroll
  for (int j=0;j<16;j++) pp[j] = acc[j];
}

// reduce partials, emit bf16 TRANSPOSED: kvb[bh][e][d]  (B-operand layout for mfma)
__global__ __launch_bounds__(256) void kv_reduce(const float* __restrict__ part,
                                                 unsigned short* __restrict__ kvb){
  int i = blockIdx.x*256 + threadIdx.x;    // 64*4096 total; i = bh*4096 + d*64 + e
  float s = 0.f;
  #pragma unroll
  for (int c=0;c<8;c++) s += part[(size_t)c*262144 + i];
  int bh = i >> 12, de = i & 4095;
  int d = de >> 6, e = de & 63;
  kvb[(bh<<12) + e*64 + d] = f2b(s);
}

// ---------------- fused attention GEMM + depthwise conv + gated combine ----------------
// Per block: (b,h) head, 128-row t-chunk. y_att = phi(q)[128x64] @ kvb^T[64x64] via MFMA,
// epilogue mixes with conv(xn) under sigmoid gate. Writes y (bf16) in place of gsig buffer.
__global__ __launch_bounds__(256) void attn_mfma(
    const unsigned short* __restrict__ qkv, const unsigned short* __restrict__ kvb,
    const unsigned short* __restrict__ xn, const unsigned short* __restrict__ gsig,
    const float* __restrict__ conv_w, const float* __restrict__ conv_b,
    unsigned short* __restrict__ y){
  int bh = blockIdx.x;
  int b = bh >> 4, h = bh & 15;
  int t0 = blockIdx.y * 128;
  int tid = threadIdx.x, lane = tid & 63, wv = tid >> 6;
  __shared__ unsigned short sA[128*72];   // phi(q) rows, stride 72 (pad: breaks 128B bank wrap)
  __shared__ unsigned short sB[64*72];    // kv[e][d]
  // stage A: 128 rows x 64 cols bf16, phi = elu+1 applied
  #pragma unroll
  for (int it=0; it<4; it++){
    int idx = it*256 + tid;         // 0..1023 chunks of 8 shorts
    int r = idx >> 3, c = (idx & 7)*8;
    size_t gaddr = ((size_t)(b*T_ + t0 + r))*3072 + h*64 + c;
    bf16x8 u = *(const bf16x8*)(qkv + gaddr);
    bf16x8 o;
    #pragma unroll
    for (int q=0;q<8;q++){
      float f = b2f((unsigned short)u[q]);
      f = f > 0.f ? f + 1.f : __expf(f);
      o[q] = (short)f2b(f);
    }
    *(bf16x8*)(sA + r*72 + c) = o;
  }
  // stage B: kvb[bh] 64x64
  #pragma unroll
  for (int it=0; it<2; it++){
    int idx = it*256 + tid;         // 0..511 chunks of 8 shorts
    int r = idx >> 3, c = (idx & 7)*8;
    *(bf16x8*)(sB + r*72 + c) = *(const bf16x8*)(kvb + ((size_t)bh<<12) + r*64 + c);
  }
  __syncthreads();
  // fragments: wave wv owns rows [wv*32, wv*32+32), all 64 cols
  int fr = lane & 15, fk = (lane >> 4)*8;
  bf16x8 af[2][2], bfr[4][2];
  #pragma unroll
  for (int i=0;i<2;i++)
    #pragma unroll
    for (int ks=0;ks<2;ks++)
      af[i][ks] = *(const bf16x8*)(sA + (wv*32 + i*16 + fr)*72 + ks*32 + fk);
  #pragma unroll
  for (int j=0;j<4;j++)
    #pragma unroll
    for (int ks=0;ks<2;ks++)
      bfr[j][ks] = *(const bf16x8*)(sB + (j*16 + fr)*72 + ks*32 + fk);
  f32x4 zero = {0.f,0.f,0.f,0.f};
  f32x4 acc[2][4];
  #pragma unroll
  for (int i=0;i<2;i++){ acc[i][0]=zero; acc[i][1]=zero; acc[i][2]=zero; acc[i][3]=zero; }
  #pragma unroll
  for (int ks=0;ks<2;ks++)
    #pragma unroll
    for (int i=0;i<2;i++)
      #pragma unroll
      for (int j=0;j<4;j++)
        acc[i][j] = __builtin_amdgcn_mfma_f32_16x16x32_bf16(af[i][ks], bfr[j][ks], acc[i][j], 0,0,0);
  // epilogue: C/D layout col=lane&15, row=(lane>>4)*4+reg
  int er = (lane>>4)*4, ec = lane & 15;
  #pragma unroll
  for (int j=0;j<4;j++){
    int d = h*64 + j*16 + ec;
    float w0 = conv_w[d*3], w1 = conv_w[d*3+1], w2 = conv_w[d*3+2], cb = conv_b[d];
    #pragma unroll
    for (int i=0;i<2;i++){
      #pragma unroll
      for (int r=0;r<4;r++){
        int t = t0 + wv*32 + i*16 + er + r;       // local t within batch
        size_t base = ((size_t)(b*T_ + t))*1024 + d;
        float ya = acc[i][j][r];
        float xm = (t>0)      ? b2f(xn[base-1024]) : 0.f;
        float xc =              b2f(xn[base]);
        float xp = (t<T_-1)   ? b2f(xn[base+1024]) : 0.f;
        float yl = xm*w0 + xc*w1 + xp*w2 + cb;
        float gg = b2f(gsig[base]);
        y[base] = f2b(gg*ya + (1.f-gg)*yl);
      }
    }
  }
}

extern "C" void kernel_launch(void* const* d_in, const int* in_sizes, int n_in,
                              void* d_out, int out_size, void* d_ws, size_t ws_size,
                              hipStream_t stream){
  const float* x      = (const float*)d_in[0];
  const float* ln_g   = (const float*)d_in[1];
  const float* ln_b   = (const float*)d_in[2];
  const float* w_qkv  = (const float*)d_in[3];
  const float* conv_w = (const float*)d_in[4];
  const float* conv_b = (const float*)d_in[5];
  const float* gln_g  = (const float*)d_in[6];
  const float* gln_b  = (const float*)d_in[7];
  const float* w_gate = (const float*)d_in[8];
  const float* b_gate = (const float*)d_in[9];
  const float* w_out  = (const float*)d_in[10];
  const float* b_out  = (const float*)d_in[11];
  float* out = (float*)d_out;

  char* ws = (char*)d_ws;
  size_t off = 0;
  auto alloc = [&](size_t bytes){ void* p = ws + off; off += (bytes + 255) & ~(size_t)255; return p; };
  unsigned short* wqkv_b  = (unsigned short*)alloc((size_t)3072*1024*2);
  unsigned short* wgate_b = (unsigned short*)alloc((size_t)1024*1024*2);
  unsigned short* wout_b  = (unsigned short*)alloc((size_t)1024*1024*2);
  unsigned short* xn      = (unsigned short*)alloc((size_t)M_*D_*2);
  unsigned short* xg      = (unsigned short*)alloc((size_t)M_*D_*2);
  unsigned short* qkv     = (unsigned short*)alloc((size_t)M_*3072*2);
  unsigned short* gy      = (unsigned short*)alloc((size_t)M_*D_*2);  // gate sigmoid, then y in-place
  float* part             = (float*)alloc((size_t)8*64*4096*4);
  unsigned short* kvb     = (unsigned short*)alloc((size_t)64*4096*2);

  f32_to_bf16<<<3072*1024/1024, 256, 0, stream>>>(w_qkv,  wqkv_b,  3072*1024);
  f32_to_bf16<<<1024*1024/1024, 256, 0, stream>>>(w_gate, wgate_b, 1024*1024);
  f32_to_bf16<<<1024*1024/1024, 256, 0, stream>>>(w_out,  wout_b,  1024*1024);

  ln_dual<<<M_, 256, 0, stream>>>(x, ln_g, ln_b, gln_g, gln_b, xn, xg);

  // qkv = xn @ w_qkv^T   [16384,3072]
  gemm_bt<0><<<dim3(128,24), 256, 0, stream>>>(xn, wqkv_b, 3072, 1024, nullptr, nullptr, qkv, nullptr);

  // kv state per (b,h)
  kv_partial<<<dim3(64,8), 256, 0, stream>>>(qkv, part);
  kv_reduce<<<1024, 256, 0, stream>>>(part, kvb);

  // g = sigmoid(xg @ w_gate^T + b_gate)
  gemm_bt<1><<<dim3(128,8), 256, 0, stream>>>(xg, wgate_b, 1024, 1024, b_gate, nullptr, gy, nullptr);

  // y = g*y_att + (1-g)*y_local  (fused MFMA attention + conv + gate; in-place over gy)
  attn_mfma<<<dim3(64,32), 256, 0, stream>>>(qkv, kvb, xn, gy, conv_w, conv_b, gy);

  // out = x + y @ w_out^T + b_out
  gemm_bt<2><<<dim3(128,8), 256, 0, stream>>>(gy, wout_b, 1024, 1024, b_out, x, nullptr, out);
}

// Round 3
// 473.814 us; speedup vs baseline: 1.3300x; 1.0529x over previous
//
#include <hip/hip_runtime.h>
#include <hip/hip_bf16.h>

// GLA block: LN -> QKV -> ELU linear attention + depthwise conv -> gated mix -> out proj + residual
// B=4 T=4096 D=1024 H=16 HD=64 K=3
#define B_ 4
#define T_ 4096
#define D_ 1024
#define H_ 16
#define M_ (B_*T_)      // 16384 rows
#define KV_CHUNKS 16

typedef short bf16x8 __attribute__((ext_vector_type(8)));
typedef float f32x4 __attribute__((ext_vector_type(4)));

__device__ __forceinline__ float b2f(unsigned short h){
  union { unsigned u; float f; } x; x.u = ((unsigned)h) << 16; return x.f;
}
__device__ __forceinline__ unsigned short f2b(float f){
  union { float f; unsigned u; } x; x.f = f;
  unsigned r = x.u + 0x7FFFu + ((x.u >> 16) & 1u);   // RNE
  return (unsigned short)(r >> 16);
}

// async global->LDS, 16B per lane. LDS dst must be wave-uniform (HW scatters lane*16).
__device__ __forceinline__ void ld_lds16(const unsigned short* g, unsigned short* l){
  __builtin_amdgcn_global_load_lds(
      (const __attribute__((address_space(1))) unsigned int*)(unsigned long long)g,
      (__attribute__((address_space(3))) unsigned int*)(unsigned int)(unsigned long long)l,
      16, 0, 0);
}

// ---------------- fp32 -> bf16 weight convert ----------------
__global__ __launch_bounds__(256) void f32_to_bf16(const float* __restrict__ src,
                                                   unsigned short* __restrict__ dst, int n){
  int i = (blockIdx.x*256 + threadIdx.x)*4;
  if (i < n){
    float4 v = *(const float4*)(src + i);
    ushort4 o; o.x=f2b(v.x); o.y=f2b(v.y); o.z=f2b(v.z); o.w=f2b(v.w);
    *(ushort4*)(dst + i) = o;
  }
}

// ---------------- dual LayerNorm (shared mean/var) ----------------
__global__ __launch_bounds__(256) void ln_dual(
    const float* __restrict__ x,
    const float* __restrict__ g1, const float* __restrict__ b1,
    const float* __restrict__ g2, const float* __restrict__ b2,
    unsigned short* __restrict__ xn, unsigned short* __restrict__ xg){
  int row = blockIdx.x;
  int tid = threadIdx.x;
  const float4* xr = (const float4*)(x + (size_t)row*D_);
  float4 v = xr[tid];
  float s  = v.x+v.y+v.z+v.w;
  float ss = v.x*v.x + v.y*v.y + v.z*v.z + v.w*v.w;
  #pragma unroll
  for (int o=32;o>0;o>>=1){ s += __shfl_down(s,o,64); ss += __shfl_down(ss,o,64); }
  __shared__ float red[8];
  int lane = tid & 63, wv = tid >> 6;
  if (lane==0){ red[wv]=s; red[4+wv]=ss; }
  __syncthreads();
  s  = red[0]+red[1]+red[2]+red[3];
  ss = red[4]+red[5]+red[6]+red[7];
  float mean = s * (1.f/D_);
  float var  = ss*(1.f/D_) - mean*mean;
  float inv  = rsqrtf(var + 1e-5f);
  int c = tid*4;
  float4 ga = *(const float4*)(g1+c), ba = *(const float4*)(b1+c);
  float4 gb = *(const float4*)(g2+c), bb = *(const float4*)(b2+c);
  float nx=(v.x-mean)*inv, ny=(v.y-mean)*inv, nz=(v.z-mean)*inv, nw=(v.w-mean)*inv;
  size_t base = (size_t)row*D_ + c;
  ushort4 o1, o2;
  o1.x=f2b(nx*ga.x+ba.x); o1.y=f2b(ny*ga.y+ba.y); o1.z=f2b(nz*ga.z+ba.z); o1.w=f2b(nw*ga.w+ba.w);
  o2.x=f2b(nx*gb.x+bb.x); o2.y=f2b(ny*gb.y+bb.y); o2.z=f2b(nz*gb.z+bb.z); o2.w=f2b(nw*gb.w+bb.w);
  *(ushort4*)(xn+base) = o1;
  *(ushort4*)(xg+base) = o2;
}

// ---------------- bf16 MFMA GEMM: C[m,n] = sum_k A[m,k]*Bw[n,k] (+epilogue) ----------------
// LDS 16B-chunk XOR swizzle: position p of row r holds global chunk p ^ ((r>>1)&3).
// Breaks the 8-way ds_read_b128 bank conflict (row stride 64B) down to 2-way (free).
// EPI 0: store bf16 raw. EPI 1: +bias, sigmoid, store bf16. EPI 2: +bias+resid, store fp32.
template<int EPI>
__global__ __launch_bounds__(256, 3) void gemm_bt(
    const unsigned short* __restrict__ A, const unsigned short* __restrict__ Bw,
    int N, int K,
    const float* __restrict__ bias, const float* __restrict__ resid,
    unsigned short* __restrict__ Cb, float* __restrict__ Cf){
  __shared__ unsigned short sA[128*32];
  __shared__ unsigned short sB[128*32];
  int tid = threadIdx.x;
  int lane = tid & 63, wv = tid >> 6;
  int m0 = blockIdx.x * 128, n0 = blockIdx.y * 128;
  int srow = wv*32 + (lane>>2);
  int scol = (((lane&3) ^ ((lane>>3)&3)))*8;   // source chunk swizzled by row parity
  const unsigned short* gA = A + (size_t)(m0+srow)*K + scol;
  const unsigned short* gB = Bw + (size_t)(n0+srow)*K + scol;
  unsigned short* lA = sA + wv*1024;   // wave-uniform
  unsigned short* lB = sB + wv*1024;
  f32x4 zero = {0.f,0.f,0.f,0.f};
  f32x4 acc[4][4];
  #pragma unroll
  for (int i=0;i<4;i++){ acc[i][0]=zero; acc[i][1]=zero; acc[i][2]=zero; acc[i][3]=zero; }
  int wm = wv & 1, wn = wv >> 1;
  int fr = lane & 15;
  int fk = ((lane >> 4) * 8) ^ (((fr>>1)&3)<<3);   // chunk un-swizzle on read
  for (int kk = 0; kk < K; kk += 32){
    __syncthreads();
    ld_lds16(gA,              lA);
    ld_lds16(gA + (size_t)16*K, lA + 512);
    ld_lds16(gB,              lB);
    ld_lds16(gB + (size_t)16*K, lB + 512);
    gA += 32; gB += 32;
    __syncthreads();
    bf16x8 af[4], bfr[4];
    #pragma unroll
    for (int i=0;i<4;i++) af[i]  = *(const bf16x8*)(sA + (wm*64 + i*16 + fr)*32 + fk);
    #pragma unroll
    for (int j=0;j<4;j++) bfr[j] = *(const bf16x8*)(sB + (wn*64 + j*16 + fr)*32 + fk);
    #pragma unroll
    for (int i=0;i<4;i++)
      #pragma unroll
      for (int j=0;j<4;j++)
        acc[i][j] = __builtin_amdgcn_mfma_f32_16x16x32_bf16(af[i], bfr[j], acc[i][j], 0,0,0);
  }
  int er = (lane>>4)*4;
  int ec = lane & 15;
  #pragma unroll
  for (int i=0;i<4;i++){
    #pragma unroll
    for (int r=0;r<4;r++){
      int m = m0 + wm*64 + i*16 + er + r;
      size_t rowoff = (size_t)m * N;
      #pragma unroll
      for (int j=0;j<4;j++){
        int n = n0 + wn*64 + j*16 + ec;
        float v = acc[i][j][r];
        if (EPI == 0){
          Cb[rowoff + n] = f2b(v);
        } else if (EPI == 1){
          v += bias[n];
          v = 1.f/(1.f + __expf(-v));
          Cb[rowoff + n] = f2b(v);
        } else {
          v += bias[n] + resid[rowoff + n];
          Cf[rowoff + n] = v;
        }
      }
    }
  }
}

// ---------------- kv partials: kv[b,h,d,e] = sum_t phi_k[t,d]*v[t,e] ----------------
__global__ __launch_bounds__(256) void kv_partial(const unsigned short* __restrict__ qkv,
                                                  float* __restrict__ part){
  int bh = blockIdx.x, chunk = blockIdx.y;
  int b = bh >> 4, h = bh & 15;
  int tid = threadIdx.x;
  int d = tid & 63, wv = tid >> 6;
  __shared__ float sk[512], sv[512];    // 8 timesteps x 64
  float acc[16];
  #pragma unroll
  for (int j=0;j<16;j++) acc[j] = 0.f;
  size_t base = ((size_t)(b*T_) + (size_t)chunk*(T_/KV_CHUNKS)) * 3072 + h*64;
  for (int ts=0; ts<(T_/KV_CHUNKS); ts+=8){
    __syncthreads();
    int li = tid & 127;
    int tt = li >> 4;
    int e  = (li & 15) * 4;
    size_t off = base + (size_t)(ts+tt)*3072 + e;
    if (tid < 128){
      ushort4 kr = *(const ushort4*)(qkv + off + 1024);
      float k0=b2f(kr.x), k1=b2f(kr.y), k2=b2f(kr.z), k3=b2f(kr.w);
      float4 ph;
      ph.x = k0>0.f ? k0+1.f : __expf(k0);
      ph.y = k1>0.f ? k1+1.f : __expf(k1);
      ph.z = k2>0.f ? k2+1.f : __expf(k2);
      ph.w = k3>0.f ? k3+1.f : __expf(k3);
      *(float4*)(sk + tt*64 + e) = ph;
    } else {
      ushort4 vr = *(const ushort4*)(qkv + off + 2048);
      float4 vv; vv.x=b2f(vr.x); vv.y=b2f(vr.y); vv.z=b2f(vr.z); vv.w=b2f(vr.w);
      *(float4*)(sv + tt*64 + e) = vv;
    }
    __syncthreads();
    #pragma unroll
    for (int t8=0;t8<8;t8++){
      float pk = sk[t8*64 + d];
      const float4* v4 = (const float4*)(sv + t8*64 + wv*16);
      float4 a0=v4[0], a1=v4[1], a2=v4[2], a3=v4[3];
      acc[0] +=pk*a0.x; acc[1] +=pk*a0.y; acc[2] +=pk*a0.z; acc[3] +=pk*a0.w;
      acc[4] +=pk*a1.x; acc[5] +=pk*a1.y; acc[6] +=pk*a1.z; acc[7] +=pk*a1.w;
      acc[8] +=pk*a2.x; acc[9] +=pk*a2.y; acc[10]+=pk*a2.z; acc[11]+=pk*a2.w;
      acc[12]+=pk*a3.x; acc[13]+=pk*a3.y; acc[14]+=pk*a3.w==0?pk*a3.z:pk*a3.z; acc[15]+=pk*a3.w;
    }
  }
  float* pp = part + (((size_t)chunk*64 + bh)*4096) + d*64 + wv*16;
  #pragma unroll
  for (int j=0;j<16;j++) pp[j] = acc[j];
}

// reduce partials, emit bf16 TRANSPOSED: kvb[bh][e][d]  (B-operand layout for mfma)
__global__ __launch_bounds__(256) void kv_reduce(const float* __restrict__ part,
                                                 unsigned short* __restrict__ kvb){
  int i = blockIdx.x*256 + threadIdx.x;    // 64*4096 total; i = bh*4096 + d*64 + e
  float s = 0.f;
  #pragma unroll
  for (int c=0;c<KV_CHUNKS;c++) s += part[(size_t)c*262144 + i];
  int bh = i >> 12, de = i & 4095;
  int d = de >> 6, e = de & 63;
  kvb[(bh<<12) + e*64 + d] = f2b(s);
}

// ---------------- fused attention GEMM + depthwise conv + gated combine ----------------
// Per block: (b,h) head, 128-row t-chunk. y_att = phi(q)[128x64] @ kvb^T[64x64] via MFMA.
// Acc round-trips through LDS (f32 tile) so the epilogue is row-major vectorized:
// ushort8 loads of xn/gsig, ushort8 store of y. conv params staged in LDS.
__global__ __launch_bounds__(256) void attn_mfma(
    const unsigned short* __restrict__ qkv, const unsigned short* __restrict__ kvb,
    const unsigned short* __restrict__ xn, const unsigned short* __restrict__ gsig,
    const float* __restrict__ conv_w, const float* __restrict__ conv_b,
    unsigned short* __restrict__ y){
  int bh = blockIdx.x;
  int b = bh >> 4, h = bh & 15;
  int t0 = blockIdx.y * 128;
  int tid = threadIdx.x, lane = tid & 63, wv = tid >> 6;
  __shared__ __align__(16) char smem[128*68*4];   // union: {sA 18KB + sB 9KB} then sC 34.8KB
  unsigned short* sA = (unsigned short*)smem;     // 128 x 72 (pad 72 kills frag-read conflicts)
  unsigned short* sB = sA + 128*72;               // 64 x 72
  float* sC = (float*)smem;                       // 128 x 68
  __shared__ float sW[64*4];                      // conv w0,w1,w2,bias for this head's 64 ch
  if (tid < 64){
    int d = h*64 + tid;
    sW[tid*4+0] = conv_w[d*3];
    sW[tid*4+1] = conv_w[d*3+1];
    sW[tid*4+2] = conv_w[d*3+2];
    sW[tid*4+3] = conv_b[d];
  }
  // stage A: 128 rows x 64 cols bf16, phi = elu+1 applied
  #pragma unroll
  for (int it=0; it<4; it++){
    int idx = it*256 + tid;         // 0..1023 chunks of 8 shorts
    int r = idx >> 3, c = (idx & 7)*8;
    size_t gaddr = ((size_t)(b*T_ + t0 + r))*3072 + h*64 + c;
    bf16x8 u = *(const bf16x8*)(qkv + gaddr);
    bf16x8 o;
    #pragma unroll
    for (int q=0;q<8;q++){
      float f = b2f((unsigned short)u[q]);
      f = f > 0.f ? f + 1.f : __expf(f);
      o[q] = (short)f2b(f);
    }
    *(bf16x8*)(sA + r*72 + c) = o;
  }
  // stage B: kvb[bh] 64x64
  #pragma unroll
  for (int it=0; it<2; it++){
    int idx = it*256 + tid;
    int r = idx >> 3, c = (idx & 7)*8;
    *(bf16x8*)(sB + r*72 + c) = *(const bf16x8*)(kvb + ((size_t)bh<<12) + r*64 + c);
  }
  __syncthreads();
  int fr = lane & 15, fk = (lane >> 4)*8;
  bf16x8 af[2][2], bfr[4][2];
  #pragma unroll
  for (int i=0;i<2;i++)
    #pragma unroll
    for (int ks=0;ks<2;ks++)
      af[i][ks] = *(const bf16x8*)(sA + (wv*32 + i*16 + fr)*72 + ks*32 + fk);
  #pragma unroll
  for (int j=0;j<4;j++)
    #pragma unroll
    for (int ks=0;ks<2;ks++)
      bfr[j][ks] = *(const bf16x8*)(sB + (j*16 + fr)*72 + ks*32 + fk);
  __syncthreads();    // all LDS reads done; sC may now overwrite sA/sB
  f32x4 zero = {0.f,0.f,0.f,0.f};
  f32x4 acc[2][4];
  #pragma unroll
  for (int i=0;i<2;i++){ acc[i][0]=zero; acc[i][1]=zero; acc[i][2]=zero; acc[i][3]=zero; }
  #pragma unroll
  for (int ks=0;ks<2;ks++)
    #pragma unroll
    for (int i=0;i<2;i++)
      #pragma unroll
      for (int j=0;j<4;j++)
        acc[i][j] = __builtin_amdgcn_mfma_f32_16x16x32_bf16(af[i][ks], bfr[j][ks], acc[i][j], 0,0,0);
  // dump acc to LDS tile: C/D layout col=lane&15, row=(lane>>4)*4+reg
  int er = (lane>>4)*4, ec = lane & 15;
  #pragma unroll
  for (int i=0;i<2;i++)
    #pragma unroll
    for (int j=0;j<4;j++)
      #pragma unroll
      for (int r=0;r<4;r++)
        sC[(wv*32 + i*16 + er + r)*68 + j*16 + ec] = acc[i][j][r];
  __syncthreads();
  // row-major vectorized epilogue: thread -> (row = tid/2, 32-col half)
  int row = tid >> 1, cb0 = (tid & 1)*32;
  int t = t0 + row;
  size_t gb = ((size_t)(b*T_ + t))*1024 + h*64 + cb0;
  #pragma unroll
  for (int c8=0; c8<4; c8++){
    int cc = cb0 + c8*8;
    const float4* cp = (const float4*)(sC + row*68 + cc);
    float4 cv0 = cp[0], cv1 = cp[1];
    bf16x8 gv = *(const bf16x8*)(gsig + gb + c8*8);
    bf16x8 xc = *(const bf16x8*)(xn + gb + c8*8);
    bf16x8 xm = {0,0,0,0,0,0,0,0}, xp = {0,0,0,0,0,0,0,0};
    if (t > 0)     xm = *(const bf16x8*)(xn + gb + c8*8 - 1024);
    if (t < T_-1)  xp = *(const bf16x8*)(xn + gb + c8*8 + 1024);
    bf16x8 o;
    #pragma unroll
    for (int q=0;q<8;q++){
      const float* w = sW + (cc + q)*4;
      float yl = b2f((unsigned short)xm[q])*w[0] + b2f((unsigned short)xc[q])*w[1]
               + b2f((unsigned short)xp[q])*w[2] + w[3];
      float ya = (q < 4) ? ((const float*)&cv0)[q] : ((const float*)&cv1)[q-4];
      float gg = b2f((unsigned short)gv[q]);
      o[q] = (short)f2b(gg*ya + (1.f-gg)*yl);
    }
    *(bf16x8*)(y + gb + c8*8) = o;
  }
}

extern "C" void kernel_launch(void* const* d_in, const int* in_sizes, int n_in,
                              void* d_out, int out_size, void* d_ws, size_t ws_size,
                              hipStream_t stream){
  const float* x      = (const float*)d_in[0];
  const float* ln_g   = (const float*)d_in[1];
  const float* ln_b   = (const float*)d_in[2];
  const float* w_qkv  = (const float*)d_in[3];
  const float* conv_w = (const float*)d_in[4];
  const float* conv_b = (const float*)d_in[5];
  const float* gln_g  = (const float*)d_in[6];
  const float* gln_b  = (const float*)d_in[7];
  const float* w_gate = (const float*)d_in[8];
  const float* b_gate = (const float*)d_in[9];
  const float* w_out  = (const float*)d_in[10];
  const float* b_out  = (const float*)d_in[11];
  float* out = (float*)d_out;

  char* ws = (char*)d_ws;
  size_t off = 0;
  auto alloc = [&](size_t bytes){ void* p = ws + off; off += (bytes + 255) & ~(size_t)255; return p; };
  unsigned short* wqkv_b  = (unsigned short*)alloc((size_t)3072*1024*2);
  unsigned short* wgate_b = (unsigned short*)alloc((size_t)1024*1024*2);
  unsigned short* wout_b  = (unsigned short*)alloc((size_t)1024*1024*2);
  unsigned short* xn      = (unsigned short*)alloc((size_t)M_*D_*2);
  unsigned short* xg      = (unsigned short*)alloc((size_t)M_*D_*2);
  unsigned short* qkv     = (unsigned short*)alloc((size_t)M_*3072*2);
  unsigned short* gy      = (unsigned short*)alloc((size_t)M_*D_*2);  // gate sigmoid, then y in-place
  float* part             = (float*)alloc((size_t)KV_CHUNKS*64*4096*4);
  unsigned short* kvb     = (unsigned short*)alloc((size_t)64*4096*2);

  f32_to_bf16<<<3072*1024/1024, 256, 0, stream>>>(w_qkv,  wqkv_b,  3072*1024);
  f32_to_bf16<<<1024*1024/1024, 256, 0, stream>>>(w_gate, wgate_b, 1024*1024);
  f32_to_bf16<<<1024*1024/1024, 256, 0, stream>>>(w_out,  wout_b,  1024*1024);

  ln_dual<<<M_, 256, 0, stream>>>(x, ln_g, ln_b, gln_g, gln_b, xn, xg);

  // qkv = xn @ w_qkv^T   [16384,3072]
  gemm_bt<0><<<dim3(128,24), 256, 0, stream>>>(xn, wqkv_b, 3072, 1024, nullptr, nullptr, qkv, nullptr);

  // kv state per (b,h)
  kv_partial<<<dim3(64,KV_CHUNKS), 256, 0, stream>>>(qkv, part);
  kv_reduce<<<1024, 256, 0, stream>>>(part, kvb);

  // g = sigmoid(xg @ w_gate^T + b_gate)
  gemm_bt<1><<<dim3(128,8), 256, 0, stream>>>(xg, wgate_b, 1024, 1024, b_gate, nullptr, gy, nullptr);

  // y = g*y_att + (1-g)*y_local  (fused MFMA attention + conv + gate; in-place over gy)
  attn_mfma<<<dim3(64,32), 256, 0, stream>>>(qkv, kvb, xn, gy, conv_w, conv_b, gy);

  // out = x + y @ w_out^T + b_out
  gemm_bt<2><<<dim3(128,8), 256, 0, stream>>>(gy, wout_b, 1024, 1024, b_out, x, nullptr, out);
}